// Round 1
// baseline (2523.977 us; speedup 1.0000x reference)
//
#include <hip/hip_runtime.h>
#include <stdint.h>

#define TB 400
#define OUTROW 160000   // T * 2F
#define NTHR 256
#define GRID 256

// LDS layout (byte offsets), all 16-aligned
#define OFF_W   0        // uint32 [150][100]  W slice, bf16 k-pair packed  (60000 B)
#define OFF_P   60000    // uint32 [50][50]    P slice, bf16 s-pair packed  (10000 B)
#define OFF_B   70000    // f32 [100] bias slice                            (400 B)
#define OFF_XM  70400    // f32 [300][4] activations transposed [k][seq]    (4800 B)
#define OFF_C   75200    // f32 [4][25] cell state slice                    (400 B)
#define OFF_U   75600    // 16000 B union: gpart[10][4][100] / hlT[100][4] + ppart[10][4][50]
#define LDS_BYTES 91600

#define AGENT __HIP_MEMORY_SCOPE_AGENT

__device__ __forceinline__ float sigf(float x){ return 1.0f/(1.0f+__expf(-x)); }
__device__ __forceinline__ float tanh_fast(float x){ float e=__expf(2.0f*x); return 1.0f - 2.0f/(e+1.0f); }
__device__ __forceinline__ float blo(uint32_t u){ return __uint_as_float(u<<16); }
__device__ __forceinline__ float bhi(uint32_t u){ return __uint_as_float(u & 0xffff0000u); }
__device__ __forceinline__ uint32_t bpack(float a, float b){
  uint32_t xa=__float_as_uint(a), xb=__float_as_uint(b);
  uint32_t ra=(xa + 0x7fffu + ((xa>>16)&1u))>>16;   // RTNE bf16
  uint32_t rb=(xb + 0x7fffu + ((xb>>16)&1u))>>16;
  return (ra&0xffffu)|(rb<<16);
}

__global__ __launch_bounds__(NTHR, 1)
void lstm_bidir_kernel(const float* __restrict__ z,
                       const float* __restrict__ c0f, const float* __restrict__ m0f,
                       const float* __restrict__ c0b, const float* __restrict__ m0b,
                       const float* __restrict__ Wf, const float* __restrict__ bfv,
                       const float* __restrict__ Pf,
                       const float* __restrict__ Wb, const float* __restrict__ bbv,
                       const float* __restrict__ Pb,
                       float* __restrict__ out, char* __restrict__ ws)
{
  const int tid = threadIdx.x;
  const int bid = blockIdx.x;
  const int g   = bid & 63;     // group: members at bids {g, g+64, g+128, g+192} -> same XCD (bid%8)
  const int mj  = bid >> 6;     // member 0..3 (owns s-slice [25*mj,..), f-slice [50*mj,..))
  const int dir = g >> 5;       // 0 fwd, 1 bwd
  const int b0  = (g & 31) * 4; // 4 sequences per group

  const float* W  = dir ? Wb  : Wf;
  const float* bv = dir ? bbv : bfv;
  const float* P  = dir ? Pb  : Pf;
  const float* c0 = dir ? c0b : c0f;
  const float* m0 = dir ? m0b : m0f;

  int*   flag_h = (int*)ws;                       // [64][4]
  int*   flag_m = (int*)(ws + 1024);              // [64][4]
  float* hbuf   = (float*)(ws + 2048);            // [64][4][100]
  float* mbuf   = (float*)(ws + 2048 + 102400);   // [64][4][200]

  extern __shared__ char smem[];
  uint32_t* Wl   = (uint32_t*)(smem + OFF_W);
  uint32_t* Pl   = (uint32_t*)(smem + OFF_P);
  float* bl      = (float*)(smem + OFF_B);
  float* xmT     = (float*)(smem + OFF_XM);           // [300][4]
  float* cst     = (float*)(smem + OFF_C);            // [4][25]
  float* gpart   = (float*)(smem + OFF_U);            // [10][4][100]
  float* hlT     = (float*)(smem + OFF_U);            // [100][4]  (aliases gpart[0], phase-disjoint)
  float* ppart   = (float*)(smem + OFF_U + 1600);     // [10][4][50] (aliases gpart[1..], phase-disjoint)

  // ---- one-time: stage weight slices into LDS (bf16 k-pair packed) ----
  for (int idx = tid; idx < 15000; idx += NTHR) {
    int k2 = idx / 100, cl = idx % 100;
    int gate = cl / 25, sl = cl % 25;
    int gcol = gate*100 + mj*25 + sl;
    float f0 = W[(size_t)(2*k2)*400 + gcol];
    float f1 = W[(size_t)(2*k2+1)*400 + gcol];
    Wl[k2*100 + cl] = bpack(f0, f1);
  }
  for (int idx = tid; idx < 2500; idx += NTHR) {
    int s2 = idx / 50, fl = idx % 50;
    int gf = mj*50 + fl;
    Pl[s2*50 + fl] = bpack(P[(size_t)(2*s2)*200 + gf], P[(size_t)(2*s2+1)*200 + gf]);
  }
  if (tid < 100) {
    int hi = tid/25, sl = tid%25;       // hi = gate (bias) and seq (c0)
    bl[tid]  = bv[hi*100 + mj*25 + sl];
    cst[tid] = c0[(size_t)(b0+hi)*100 + mj*25 + sl];
  }
  for (int idx = tid; idx < 800; idx += NTHR) {
    int s = idx / 200, k = idx % 200;
    xmT[(100+k)*4 + s] = m0[(size_t)(b0+s)*200 + k];
  }
  __syncthreads();

  // hoisted thread roles
  const int q_g  = tid % 25, ks_g = tid / 25;   // gates: col-quad, k-slice (tid<250)
  const int s_d  = tid / 25, sl_d = tid % 25;   // cell:  seq, s-local     (tid<100)
  const int fp_p = tid % 25, ks_p = tid / 25;   // proj:  f-pair, k-slice  (tid<250)
  const int s_o  = tid / 50, fl_o = tid % 50;   // m-out: seq, f-local     (tid<200)

  for (int t = 0; t < TB; ++t) {
    const int tt = dir ? (TB-1-t) : t;

    // (a) load x_t -> xmT[k][s], k<100
    for (int idx = tid; idx < 400; idx += NTHR) {
      int s = idx/100, k = idx%100;
      xmT[k*4+s] = z[(size_t)(b0+s)*40000 + (size_t)tt*100 + k];
    }
    __syncthreads();                                   // A

    // (b) gates partial sums: 25 col-quads x 10 k-slices, 4 seqs in regs
    if (tid < 250) {
      float acc[4][4];
      #pragma unroll
      for (int s=0;s<4;++s){ acc[s][0]=0.f; acc[s][1]=0.f; acc[s][2]=0.f; acc[s][3]=0.f; }
      const int k2a = ks_g*15;
      #pragma unroll 3
      for (int kk=0; kk<15; ++kk) {
        int k2 = k2a + kk;
        uint4  w  = *(const uint4*)(Wl + k2*100 + 4*q_g);
        float4 xl = *(const float4*)(xmT + (2*k2)*4);
        float4 xh = *(const float4*)(xmT + (2*k2+1)*4);
        float wl0=blo(w.x), wh0=bhi(w.x), wl1=blo(w.y), wh1=bhi(w.y);
        float wl2=blo(w.z), wh2=bhi(w.z), wl3=blo(w.w), wh3=bhi(w.w);
        acc[0][0] += xl.x*wl0 + xh.x*wh0;  acc[0][1] += xl.x*wl1 + xh.x*wh1;
        acc[0][2] += xl.x*wl2 + xh.x*wh2;  acc[0][3] += xl.x*wl3 + xh.x*wh3;
        acc[1][0] += xl.y*wl0 + xh.y*wh0;  acc[1][1] += xl.y*wl1 + xh.y*wh1;
        acc[1][2] += xl.y*wl2 + xh.y*wh2;  acc[1][3] += xl.y*wl3 + xh.y*wh3;
        acc[2][0] += xl.z*wl0 + xh.z*wh0;  acc[2][1] += xl.z*wl1 + xh.z*wh1;
        acc[2][2] += xl.z*wl2 + xh.z*wh2;  acc[2][3] += xl.z*wl3 + xh.z*wh3;
        acc[3][0] += xl.w*wl0 + xh.w*wh0;  acc[3][1] += xl.w*wl1 + xh.w*wh1;
        acc[3][2] += xl.w*wl2 + xh.w*wh2;  acc[3][3] += xl.w*wl3 + xh.w*wh3;
      }
      #pragma unroll
      for (int s=0;s<4;++s)
        *(float4*)(gpart + (ks_g*4+s)*100 + 4*q_g) = make_float4(acc[s][0],acc[s][1],acc[s][2],acc[s][3]);
    }
    __syncthreads();                                   // B

    // (d) reduce partials + bias, cell update, h; publish h slice
    if (tid < 100) {
      float iv = bl[sl_d], jv = bl[25+sl_d], fv = bl[50+sl_d], ov = bl[75+sl_d];
      #pragma unroll
      for (int ks=0; ks<10; ++ks) {
        const float* gp = gpart + (ks*4+s_d)*100;
        iv += gp[sl_d]; jv += gp[25+sl_d]; fv += gp[50+sl_d]; ov += gp[75+sl_d];
      }
      float c = sigf(fv + 1.0f)*cst[tid] + sigf(iv)*tanh_fast(jv);
      cst[tid] = c;
      float h = sigf(ov)*tanh_fast(c);
      __hip_atomic_store(hbuf + (g*4+s_d)*100 + mj*25 + sl_d, h, __ATOMIC_RELAXED, AGENT);
    }
    __syncthreads();                                   // D (drains h stores)
    if (tid == 0) __hip_atomic_store(flag_h + g*4 + mj, t+1, __ATOMIC_RELAXED, AGENT);
    if (tid < 4) {
      while (__hip_atomic_load(flag_h + g*4 + tid, __ATOMIC_RELAXED, AGENT) < t+1) {}
    }
    __syncthreads();                                   // E

    // (e) gather full h -> hlT[k][s]
    for (int idx = tid; idx < 400; idx += NTHR) {
      int s = idx/100, sg = idx%100;
      hlT[sg*4+s] = __hip_atomic_load(hbuf + (g*4+s)*100 + sg, __ATOMIC_RELAXED, AGENT);
    }
    __syncthreads();                                   // F

    // (f) projection partials: 25 f-pairs x 10 k-slices, 4 seqs
    if (tid < 250) {
      float a[4][2];
      #pragma unroll
      for (int s=0;s<4;++s){ a[s][0]=0.f; a[s][1]=0.f; }
      #pragma unroll
      for (int kk=0; kk<5; ++kk) {
        int s2 = ks_p*5 + kk;
        uint2  p  = *(const uint2*)(Pl + s2*50 + 2*fp_p);
        float4 h0 = *(const float4*)(hlT + (2*s2)*4);
        float4 h1 = *(const float4*)(hlT + (2*s2+1)*4);
        float pl0=blo(p.x), ph0=bhi(p.x), pl1=blo(p.y), ph1=bhi(p.y);
        a[0][0] += h0.x*pl0 + h1.x*ph0;  a[0][1] += h0.x*pl1 + h1.x*ph1;
        a[1][0] += h0.y*pl0 + h1.y*ph0;  a[1][1] += h0.y*pl1 + h1.y*ph1;
        a[2][0] += h0.z*pl0 + h1.z*ph0;  a[2][1] += h0.z*pl1 + h1.z*ph1;
        a[3][0] += h0.w*pl0 + h1.w*ph0;  a[3][1] += h0.w*pl1 + h1.w*ph1;
      }
      #pragma unroll
      for (int s=0;s<4;++s)
        *(float2*)(ppart + (ks_p*4+s)*50 + 2*fp_p) = make_float2(a[s][0], a[s][1]);
    }
    __syncthreads();                                   // G

    // (g) proj reduce; write m to out (nontemporal) + exchange buffer
    if (tid < 200) {
      float m = 0.f;
      #pragma unroll
      for (int ks=0; ks<10; ++ks) m += ppart[(ks*4+s_o)*50 + fl_o];
      int gf = mj*50 + fl_o;
      __builtin_nontemporal_store(m, out + (size_t)(b0+s_o)*OUTROW + (size_t)tt*400 + dir*200 + gf);
      __hip_atomic_store(mbuf + (g*4+s_o)*200 + gf, m, __ATOMIC_RELAXED, AGENT);
    }
    __syncthreads();                                   // H
    if (tid == 0) __hip_atomic_store(flag_m + g*4 + mj, t+1, __ATOMIC_RELAXED, AGENT);
    if (tid < 4) {
      while (__hip_atomic_load(flag_m + g*4 + tid, __ATOMIC_RELAXED, AGENT) < t+1) {}
    }
    __syncthreads();                                   // I

    // (h) gather full m -> xmT[100+k][s] (recurrent input for next step)
    for (int idx = tid; idx < 800; idx += NTHR) {
      int s = idx/200, k = idx%200;
      xmT[(100+k)*4 + s] = __hip_atomic_load(mbuf + (g*4+s)*200 + k, __ATOMIC_RELAXED, AGENT);
    }
    // next-iter barrier A orders these writes before use
  }
}

extern "C" void kernel_launch(void* const* d_in, const int* in_sizes, int n_in,
                              void* d_out, int out_size, void* d_ws, size_t ws_size,
                              hipStream_t stream) {
  (void)in_sizes; (void)n_in; (void)out_size; (void)ws_size;
  hipFuncSetAttribute(reinterpret_cast<const void*>(&lstm_bidir_kernel),
                      hipFuncAttributeMaxDynamicSharedMemorySize, LDS_BYTES);
  // zero the flag region every call (graph-replay determinism)
  hipMemsetAsync(d_ws, 0, 2048, stream);
  lstm_bidir_kernel<<<GRID, NTHR, LDS_BYTES, stream>>>((const float*)d_in[0],
      (const float*)d_in[1], (const float*)d_in[2],
      (const float*)d_in[3], (const float*)d_in[4],
      (const float*)d_in[5], (const float*)d_in[6], (const float*)d_in[7],
      (const float*)d_in[8], (const float*)d_in[9], (const float*)d_in[10],
      (float*)d_out, (char*)d_ws);
}

// Round 3
// 1806.025 us; speedup vs baseline: 1.3975x; 1.3975x over previous
//
#include <hip/hip_runtime.h>
#include <stdint.h>

#define TB     400
#define OUTROW 160000   // T * 2F
#define NTHR   256
#define GRID   256
#define AGENT  __HIP_MEMORY_SCOPE_AGENT

typedef _Float16 half2_t __attribute__((ext_vector_type(2)));

// LDS byte offsets (all 16-aligned)
#define OFF_W4  0        // uint32[75*200*2] W slice, f16 k-pair packed, [k4][c][u]  (120000 B)
#define OFF_P4  120000   // uint32[13*200*2] P rows (local 50 k, zero-pad to 52)     (20800 B)
#define OFF_BL  140800   // f32[200] bias slice                                      (800 B)
#define OFF_XP  141600   // uint32[150][2] packed activations [k2][seq]              (1200 B)
#define OFF_GA  142800   // f32[2][200] gate pre-activations                         (1600 B)
#define OFF_H2  144400   // uint32[2][26] packed h (pad slot 25 = 0)                 (224 B)
#define OFF_CS  144624   // f32[100] cell state                                      (400 B)
#define LDS_BYTES 145024

#if defined(__has_builtin)
#  if __has_builtin(__builtin_amdgcn_fdot2)
#    define HAVE_FDOT2 1
#  endif
#endif

__device__ __forceinline__ float sigf(float x){ return 1.0f/(1.0f+__expf(-x)); }
__device__ __forceinline__ float tanhf_(float x){ float e=__expf(2.0f*x); return 1.0f - 2.0f/(e+1.0f); }
__device__ __forceinline__ uint32_t pkh(float a, float b){
  half2_t h; h.x = (_Float16)a; h.y = (_Float16)b;
  return __builtin_bit_cast(uint32_t, h);
}
__device__ __forceinline__ float hget(uint32_t u, int hi){
  half2_t h = __builtin_bit_cast(half2_t, u);
  float lo = (float)h.x, hv = (float)h.y;
  return hi ? hv : lo;
}
__device__ __forceinline__ float dot2f(uint32_t w, uint32_t x, float acc){
#ifdef HAVE_FDOT2
  return __builtin_amdgcn_fdot2(__builtin_bit_cast(half2_t, w),
                                __builtin_bit_cast(half2_t, x), acc, false);
#else
  half2_t a = __builtin_bit_cast(half2_t, w), b = __builtin_bit_cast(half2_t, x);
  return acc + (float)a.x*(float)b.x + (float)a.y*(float)b.y;
#endif
}

__global__ __launch_bounds__(NTHR, 1)
void lstm_bidir_v2(const float* __restrict__ z,
                   const float* __restrict__ c0f, const float* __restrict__ m0f,
                   const float* __restrict__ c0b, const float* __restrict__ m0b,
                   const float* __restrict__ Wf, const float* __restrict__ bfv,
                   const float* __restrict__ Pf,
                   const float* __restrict__ Wb, const float* __restrict__ bbv,
                   const float* __restrict__ Pb,
                   float* __restrict__ out, char* __restrict__ ws)
{
  const int tid = threadIdx.x;
  const int bid = blockIdx.x;
  const int mj  = bid >> 7;       // member 0/1; partner at bid^128 (same XCD under bid%8 policy — perf only)
  const int gid = bid & 127;
  const int dir = gid >> 6;       // 0 fwd, 1 bwd
  const int b0  = (gid & 63) * 2; // 2 sequences per group

  const float* W  = dir ? Wb  : Wf;
  const float* bv = dir ? bbv : bfv;
  const float* P  = dir ? Pb  : Pf;
  const float* c0 = dir ? c0b : c0f;
  const float* m0 = dir ? m0b : m0f;

  int*      flags = (int*)ws;                 // [256]
  uint32_t* mbuf  = (uint32_t*)(ws + 1024);   // [256][2 parity][200] f16-pair partials

  extern __shared__ char smem[];
  uint32_t* W4 = (uint32_t*)(smem + OFF_W4);
  uint32_t* P4 = (uint32_t*)(smem + OFF_P4);
  float*    bl = (float*)(smem + OFF_BL);
  uint32_t* xp = (uint32_t*)(smem + OFF_XP);
  float*    ga = (float*)(smem + OFF_GA);
  uint32_t* h2 = (uint32_t*)(smem + OFF_H2);
  float*    cst= (float*)(smem + OFF_CS);

  // ---- one-time staging: W slice (cols gate*100+50*mj+[0,50)), P rows [50*mj,50*mj+50) ----
  for (int idx = tid; idx < 30000; idx += NTHR) {
    int u = idx & 1, rest = idx >> 1;
    int c = rest % 200, k4 = rest / 200;
    int k = 4*k4 + 2*u;
    int gc = (c/50)*100 + 50*mj + (c%50);
    W4[idx] = pkh(W[(size_t)k*400 + gc], W[(size_t)(k+1)*400 + gc]);
  }
  for (int idx = tid; idx < 5200; idx += NTHR) {
    int u = idx & 1, rest = idx >> 1;
    int f = rest % 200, k4 = rest / 200;
    int kl = 4*k4 + 2*u;
    float v0 = (kl   < 50) ? P[(size_t)(50*mj + kl    )*200 + f] : 0.f;
    float v1 = (kl+1 < 50) ? P[(size_t)(50*mj + kl + 1)*200 + f] : 0.f;
    P4[idx] = pkh(v0, v1);
  }
  if (tid < 200) bl[tid] = bv[(tid/50)*100 + 50*mj + (tid%50)];
  if (tid < 100) cst[tid] = c0[(size_t)(b0 + tid/50)*100 + 50*mj + (tid%50)];
  { // xp x-slots: x(t=0) in k2 0..49
    int tt0 = dir ? (TB-1) : 0;
    if (tid < 100) {
      int k2 = tid >> 1, s = tid & 1;
      const float* zs = z + (size_t)(b0+s)*40000 + (size_t)tt0*100;
      xp[k2*2 + s] = pkh(zs[2*k2], zs[2*k2+1]);
    }
    // xp m-slots: m0 in k2 50..149 — FULL 200 (j,s) pairs (R2 bug: only j<78 covered)
    for (int u = tid; u < 200; u += NTHR) {
      int j = u >> 1, s = u & 1;
      const float* ms = m0 + (size_t)(b0+s)*200;
      xp[(50+j)*2 + s] = pkh(ms[2*j], ms[2*j+1]);
    }
  }
  __syncthreads();

  // shared GEMM body: acc += W4[k4 range] . xp   (thread = col c, 2 seq accumulators)
  #define GEMM_PART(K4LO, K4HI, A0, A1)                              \
    { _Pragma("unroll 5")                                            \
      for (int k4 = (K4LO); k4 < (K4HI); ++k4) {                     \
        uint2 w  = *(const uint2*)(W4 + (k4*200 + tid)*2);           \
        uint4 xq = *(const uint4*)(xp + 4*k4);                       \
        A0 = dot2f(w.x, xq.x, A0);                                   \
        A1 = dot2f(w.x, xq.y, A1);                                   \
        A0 = dot2f(w.y, xq.z, A0);                                   \
        A1 = dot2f(w.y, xq.w, A1);                                   \
      } }

  float accx0 = 0.f, accx1 = 0.f;              // x-part gate partials (k 0..99), carried across steps
  if (tid < 200) { accx0 = bl[tid]; accx1 = accx0; GEMM_PART(0, 25, accx0, accx1); }

  for (int t = 0; t < TB; ++t) {
    const int tt = dir ? (TB-1-t) : t;
    __syncthreads();                                     // A: xp m-part ready
    // 1) gates m-part (k 100..299) on top of carried x-part
    if (tid < 200) {
      float a0 = accx0, a1 = accx1;
      GEMM_PART(25, 75, a0, a1);
      ga[tid] = a0; ga[200+tid] = a1;
    }
    // 2) prefetch x(t+1) -> register
    float xreg = 0.f;
    if (tid < 200 && t+1 < TB) {
      int s = tid/100, k = tid%100;
      int ttn = dir ? (TB-2-t) : (t+1);
      xreg = z[(size_t)(b0+s)*40000 + (size_t)ttn*100 + k];
    }
    __syncthreads();                                     // B
    // 3) cell update + h pack (f16 pairs via shfl)
    if (tid < 100) {
      int s = tid/50, sl = tid%50;
      const float* g = ga + s*200;
      float iv=g[sl], jv=g[50+sl], fv=g[100+sl], ov=g[150+sl];
      float cc = sigf(fv + 1.0f)*cst[tid] + sigf(iv)*tanhf_(jv);
      cst[tid] = cc;
      float h = sigf(ov)*tanhf_(cc);
      float hn = __shfl_xor(h, 1);
      if ((sl & 1) == 0) h2[s*26 + (sl>>1)] = pkh(h, hn);
      if (sl == 0) h2[s*26 + 25] = 0u;                   // pad (paired with zero P rows)
    }
    __syncthreads();                                     // C
    // 4) projection partial over local 50 k; store f16-pair partial to mbuf[parity]
    float p0 = 0.f, p1 = 0.f;
    if (tid < 200) {
      #pragma unroll
      for (int k4 = 0; k4 < 13; ++k4) {
        uint2 pw = *(const uint2*)(P4 + (k4*200 + tid)*2);
        uint2 ha = *(const uint2*)(h2 + 2*k4);
        uint2 hb = *(const uint2*)(h2 + 26 + 2*k4);
        p0 = dot2f(pw.x, ha.x, p0); p0 = dot2f(pw.y, ha.y, p0);
        p1 = dot2f(pw.x, hb.x, p1); p1 = dot2f(pw.y, hb.y, p1);
      }
      float q0 = __shfl_xor(p0, 1), q1 = __shfl_xor(p1, 1);
      if ((tid & 1) == 0) {
        uint32_t* dst = mbuf + ((size_t)bid*2 + (t&1))*200;
        __hip_atomic_store(dst + (tid>>1),       pkh(p0,q0), __ATOMIC_RELAXED, AGENT);
        __hip_atomic_store(dst + 100 + (tid>>1), pkh(p1,q1), __ATOMIC_RELAXED, AGENT);
      }
      // 5) pack x(t+1) into xp x-slots (read at step 7, ordered by barrier D)
      if (t+1 < TB) {
        float xn = __shfl_xor(xreg, 1);
        if ((tid & 1) == 0) {
          int s = tid/100, k = tid%100;
          xp[(k>>1)*2 + s] = pkh(xreg, xn);
        }
      }
    }
    __syncthreads();                                     // D: drains partial stores + orders xp writes
    // 6) publish flag
    if (tid == 0) __hip_atomic_store(flags + bid, t+1, __ATOMIC_RELAXED, AGENT);
    // 7) x-part of NEXT step's gates — overlaps the exchange latency
    if (tid < 200 && t+1 < TB) {
      accx0 = bl[tid]; accx1 = accx0;
      GEMM_PART(0, 25, accx0, accx1);
    }
    // 8) wait for partner's partial
    if (tid == 0) {
      while (__hip_atomic_load(flags + (bid^128), __ATOMIC_RELAXED, AGENT) < t+1) {}
    }
    __syncthreads();                                     // E
    // 9) m = own + remote partial; write out (own f-half); pack m into xp m-slots
    if (tid < 200) {
      const uint32_t* src = mbuf + ((size_t)(bid^128)*2 + (t&1))*200;
      uint32_t r0 = __hip_atomic_load(src + (tid>>1),       __ATOMIC_RELAXED, AGENT);
      uint32_t r1 = __hip_atomic_load(src + 100 + (tid>>1), __ATOMIC_RELAXED, AGENT);
      float m0v = p0 + hget(r0, tid & 1);
      float m1v = p1 + hget(r1, tid & 1);
      if (tid/100 == mj) {
        size_t ob = (size_t)tt*400 + (size_t)dir*200 + tid;
        __builtin_nontemporal_store(m0v, out + (size_t)(b0+0)*OUTROW + ob);
        __builtin_nontemporal_store(m1v, out + (size_t)(b0+1)*OUTROW + ob);
      }
      float n0 = __shfl_xor(m0v, 1), n1 = __shfl_xor(m1v, 1);
      if ((tid & 1) == 0) {
        xp[(50 + (tid>>1))*2 + 0] = pkh(m0v, n0);
        xp[(50 + (tid>>1))*2 + 1] = pkh(m1v, n1);
      }
    }
  }
}

extern "C" void kernel_launch(void* const* d_in, const int* in_sizes, int n_in,
                              void* d_out, int out_size, void* d_ws, size_t ws_size,
                              hipStream_t stream) {
  (void)in_sizes; (void)n_in; (void)out_size; (void)ws_size;
  hipFuncSetAttribute(reinterpret_cast<const void*>(&lstm_bidir_v2),
                      hipFuncAttributeMaxDynamicSharedMemorySize, LDS_BYTES);
  hipMemsetAsync(d_ws, 0, 1024, stream);   // flags only; mbuf is parity-buffered
  lstm_bidir_v2<<<GRID, NTHR, LDS_BYTES, stream>>>((const float*)d_in[0],
      (const float*)d_in[1], (const float*)d_in[2],
      (const float*)d_in[3], (const float*)d_in[4],
      (const float*)d_in[5], (const float*)d_in[6], (const float*)d_in[7],
      (const float*)d_in[8], (const float*)d_in[9], (const float*)d_in[10],
      (float*)d_out, (char*)d_ws);
}

// Round 4
// 634.668 us; speedup vs baseline: 3.9768x; 2.8456x over previous
//
#include <hip/hip_runtime.h>
#include <stdint.h>

#define TB     400
#define OUTROW 160000   // T * 2F
#define NTHR   512
#define GRID   256      // (dir 2) x (seq 128), one block per sequence per direction

typedef _Float16 half2_t __attribute__((ext_vector_type(2)));

#if defined(__has_builtin)
#  if __has_builtin(__builtin_amdgcn_fdot2)
#    define HAVE_FDOT2 1
#  endif
#endif

__device__ __forceinline__ float sigf(float x){ return 1.0f/(1.0f+__expf(-x)); }
__device__ __forceinline__ float tanhf_(float x){ float e=__expf(2.0f*x); return 1.0f - 2.0f/(e+1.0f); }
__device__ __forceinline__ uint32_t pkh(float a, float b){
  half2_t h; h.x = (_Float16)a; h.y = (_Float16)b;
  return __builtin_bit_cast(uint32_t, h);
}
__device__ __forceinline__ float dot2f(uint32_t w, uint32_t x, float acc){
#ifdef HAVE_FDOT2
  return __builtin_amdgcn_fdot2(__builtin_bit_cast(half2_t, w),
                                __builtin_bit_cast(half2_t, x), acc, false);
#else
  half2_t a = __builtin_bit_cast(half2_t, w), b = __builtin_bit_cast(half2_t, x);
  return acc + (float)a.x*(float)b.x + (float)a.y*(float)b.y;
#endif
}

// K layout (gates): k' 0..99 = x rows, k' 100..299 = m rows, k' 300..303 = zero pad.
// xp pair-slots: [0,50) = x, [50,150) = m, [150,152) = zero pad (written once).
// Proj K: hk 0..99 = h rows, 100..111 zero pad; h2 pair-slots [0,50) h, [50,56) pad.

__global__ __launch_bounds__(NTHR, 2)
void lstm_v4(const float* __restrict__ z,
             const float* __restrict__ c0f, const float* __restrict__ m0f,
             const float* __restrict__ c0b, const float* __restrict__ m0b,
             const float* __restrict__ Wf, const float* __restrict__ bfv,
             const float* __restrict__ Pf,
             const float* __restrict__ Wb, const float* __restrict__ bbv,
             const float* __restrict__ Pb,
             float* __restrict__ out)
{
  __shared__ __align__(16) uint32_t xp[152];  // packed f16-pair activations [x | m | pad]
  __shared__ float               ga[400];     // gate pre-activations (no bias)
  __shared__ __align__(16) uint32_t h2[56];   // packed f16-pair h [h | pad]

  const int tid = threadIdx.x;
  const int dir = blockIdx.x >> 7;       // 0 fwd, 1 bwd
  const int seq = blockIdx.x & 127;

  const float* W   = dir ? Wb  : Wf;
  const float* bv  = dir ? bbv : bfv;
  const float* P   = dir ? Pb  : Pf;
  const float* c0v = dir ? c0b : c0f;
  const float* m0v = dir ? m0b : m0f;

  // ---- gates: thread owns full gate column c (c<400), W column in 38 uint4 regs ----
  const int c = tid;
  uint4 wg[38];
  if (c < 400) {
    #pragma unroll
    for (int j = 0; j < 38; ++j) {
      float f[8];
      #pragma unroll
      for (int e = 0; e < 8; ++e) {
        int kk = 8*j + e;
        f[e] = (kk < 300) ? W[(size_t)kk*400 + c] : 0.f;
      }
      wg[j] = make_uint4(pkh(f[0],f[1]), pkh(f[2],f[3]), pkh(f[4],f[5]), pkh(f[6],f[7]));
    }
  }

  // ---- proj: pidx = tid-112 in [0,400): pc = pidx>>1 (col), kp = pidx&1 (k-half) ----
  const int pidx = tid - 112;
  const int pc = pidx >> 1, kp = pidx & 1;
  uint4 pg[7];
  if (pidx >= 0) {
    #pragma unroll
    for (int j = 0; j < 7; ++j) {
      float f[8];
      #pragma unroll
      for (int e = 0; e < 8; ++e) {
        int hk = 8*(kp*7 + j) + e;
        f[e] = (hk < 100) ? P[(size_t)hk*200 + pc] : 0.f;
      }
      pg[j] = make_uint4(pkh(f[0],f[1]), pkh(f[2],f[3]), pkh(f[4],f[5]), pkh(f[6],f[7]));
    }
  }

  // ---- cell threads (c<100): state + bias in registers ----
  float cs = 0.f, bi = 0.f, bj = 0.f, bff = 0.f, bo = 0.f;
  if (c < 100) {
    cs  = c0v[(size_t)seq*100 + c];
    bi  = bv[c]; bj = bv[100+c]; bff = bv[200+c]; bo = bv[300+c];
  }

  // ---- init xp (x(t0) + m0 + pads), h2 pads ----
  if (tid < 50) {
    const float* zz = z + (size_t)seq*40000 + (size_t)(dir ? TB-1 : 0)*100;
    xp[tid] = pkh(zz[2*tid], zz[2*tid+1]);
  } else if (tid >= 64 && tid < 164) {
    int j = tid - 64;
    const float* mm = m0v + (size_t)seq*200;
    xp[50 + j] = pkh(mm[2*j], mm[2*j+1]);
  } else if (tid >= 192 && tid < 194) {
    xp[150 + (tid - 192)] = 0u;
  } else if (tid >= 256 && tid < 262) {
    h2[50 + (tid - 256)] = 0u;
  }
  __syncthreads();

  for (int t = 0; t < TB; ++t) {
    const int tt = dir ? (TB-1-t) : t;

    // x(t+1) prefetch by gates-idle threads 400..499 (hidden across gates+cell)
    float xpre = 0.f;
    if (tid >= 400 && tid < 500 && t+1 < TB) {
      int ttn = dir ? (TB-2-t) : (t+1);
      xpre = z[(size_t)seq*40000 + (size_t)ttn*100 + (tid - 400)];
    }

    // (1) gates: full-K dot per column, 4-deep broadcast prefetch
    if (c < 400) {
      float a = 0.f;
      uint4 xq[4];
      xq[0] = *(const uint4*)(xp + 0);
      xq[1] = *(const uint4*)(xp + 4);
      xq[2] = *(const uint4*)(xp + 8);
      #pragma unroll
      for (int j = 0; j < 38; ++j) {
        if (j < 35) xq[(j+3)&3] = *(const uint4*)(xp + 4*(j+3));
        uint4 xv = xq[j&3];
        a = dot2f(wg[j].x, xv.x, a);
        a = dot2f(wg[j].y, xv.y, a);
        a = dot2f(wg[j].z, xv.z, a);
        a = dot2f(wg[j].w, xv.w, a);
      }
      ga[c] = a;
    }
    __syncthreads();                                   // B: ga ready

    // (2) cell update + h pack (gate order i,j,f,o)
    if (c < 100) {
      float iv = ga[c] + bi, jv = ga[100+c] + bj, fv = ga[200+c] + bff, ov = ga[300+c] + bo;
      float cc = sigf(fv + 1.0f)*cs + sigf(iv)*tanhf_(jv);
      cs = cc;
      float h = sigf(ov)*tanhf_(cc);
      float hn = __shfl_xor(h, 1);
      if ((c & 1) == 0) h2[c >> 1] = pkh(h, hn);
    }
    __syncthreads();                                   // C: h2 ready

    // (3) projection (k-split pair) + shfl-reduce + out + m-pack
    if (pidx >= 0) {
      float p = 0.f;
      #pragma unroll
      for (int j = 0; j < 7; ++j) {
        uint4 hv = *(const uint4*)(h2 + 4*(kp*7 + j));
        p = dot2f(pg[j].x, hv.x, p);
        p = dot2f(pg[j].y, hv.y, p);
        p = dot2f(pg[j].z, hv.z, p);
        p = dot2f(pg[j].w, hv.w, p);
      }
      float m = p + __shfl_xor(p, 1);                  // sum the two k-halves (tid-pairs)
      if ((pidx & 1) == 0) {                            // even lanes hold m(pc)
        __builtin_nontemporal_store(m, out + (size_t)seq*OUTROW + (size_t)tt*400 + dir*200 + pc);
        float mn = __shfl_xor(m, 2);                   // m(pc^1) (both even lanes active)
        if ((pidx & 2) == 0) xp[50 + (pc >> 1)] = pkh(m, mn);
      }
    }
    // (4) pack x(t+1)
    if (tid >= 400 && tid < 500 && t+1 < TB) {
      float xn = __shfl_xor(xpre, 1);
      if (((tid - 400) & 1) == 0) xp[(tid - 400) >> 1] = pkh(xpre, xn);
    }
    __syncthreads();                                   // A: xp ready for next step
  }
}

extern "C" void kernel_launch(void* const* d_in, const int* in_sizes, int n_in,
                              void* d_out, int out_size, void* d_ws, size_t ws_size,
                              hipStream_t stream) {
  (void)in_sizes; (void)n_in; (void)out_size; (void)d_ws; (void)ws_size;
  lstm_v4<<<GRID, NTHR, 0, stream>>>((const float*)d_in[0],
      (const float*)d_in[1], (const float*)d_in[2],
      (const float*)d_in[3], (const float*)d_in[4],
      (const float*)d_in[5], (const float*)d_in[6], (const float*)d_in[7],
      (const float*)d_in[8], (const float*)d_in[9], (const float*)d_in[10],
      (float*)d_out);
}

// Round 5
// 634.004 us; speedup vs baseline: 3.9810x; 1.0010x over previous
//
#include <hip/hip_runtime.h>
#include <stdint.h>

#define TB     400
#define OUTROW 160000   // T * 2F
#define NTHR   512
#define GRID   256      // (dir 2) x (seq 128), one block per sequence per direction

typedef _Float16 half2_t __attribute__((ext_vector_type(2)));

#if defined(__has_builtin)
#  if __has_builtin(__builtin_amdgcn_fdot2)
#    define HAVE_FDOT2 1
#  endif
#endif

__device__ __forceinline__ float sigf(float x){ return 1.0f/(1.0f+__expf(-x)); }
__device__ __forceinline__ float tanhf_(float x){ float e=__expf(2.0f*x); return 1.0f - 2.0f/(e+1.0f); }
__device__ __forceinline__ uint32_t pkh(float a, float b){
  half2_t h; h.x = (_Float16)a; h.y = (_Float16)b;
  return __builtin_bit_cast(uint32_t, h);
}
__device__ __forceinline__ float dot2f(uint32_t w, uint32_t x, float acc){
#ifdef HAVE_FDOT2
  return __builtin_amdgcn_fdot2(__builtin_bit_cast(half2_t, w),
                                __builtin_bit_cast(half2_t, x), acc, false);
#else
  half2_t a = __builtin_bit_cast(half2_t, w), b = __builtin_bit_cast(half2_t, x);
  return acc + (float)a.x*(float)b.x + (float)a.y*(float)b.y;
#endif
}

// K layout (gates): k' 0..99 = x rows, k' 100..299 = m rows, k' 300..303 = zero pad.
// xp pair-slots: [0,50) = x, [50,150) = m, [150,152) = zero pad (written once).
// Proj K: hk 0..99 = h rows, 100..111 zero pad; h2 pair-slots [0,50) h, [50,56) pad.

__global__ __launch_bounds__(NTHR, 2)
void lstm_v5(const float* __restrict__ z,
             const float* __restrict__ c0f, const float* __restrict__ m0f,
             const float* __restrict__ c0b, const float* __restrict__ m0b,
             const float* __restrict__ Wf, const float* __restrict__ bfv,
             const float* __restrict__ Pf,
             const float* __restrict__ Wb, const float* __restrict__ bbv,
             const float* __restrict__ Pb,
             float* __restrict__ out)
{
  __shared__ __align__(16) uint32_t xp[152];  // packed f16-pair activations [x | m | pad]
  __shared__ float               ga[400];     // ACTIVATED gates
  __shared__ __align__(16) uint32_t h2[56];   // packed f16-pair h [h | pad]

  const int tid = threadIdx.x;
  const int dir = blockIdx.x >> 7;       // 0 fwd, 1 bwd
  const int seq = blockIdx.x & 127;

  const float* W   = dir ? Wb  : Wf;
  const float* bv  = dir ? bbv : bfv;
  const float* P   = dir ? Pb  : Pf;
  const float* c0v = dir ? c0b : c0f;
  const float* m0v = dir ? m0b : m0f;

  // ---- gates: thread owns full gate column c (c<400), W column in 38 uint4 regs ----
  const int c = tid;
  const int gate = c / 100;              // 0:i 1:j 2:f 3:o
  uint4 wg[38];
  float bc = 0.f;
  if (c < 400) {
    #pragma unroll
    for (int j = 0; j < 38; ++j) {
      float f[8];
      #pragma unroll
      for (int e = 0; e < 8; ++e) {
        int kk = 8*j + e;
        f[e] = (kk < 300) ? W[(size_t)kk*400 + c] : 0.f;
      }
      wg[j] = make_uint4(pkh(f[0],f[1]), pkh(f[2],f[3]), pkh(f[4],f[5]), pkh(f[6],f[7]));
    }
    bc = bv[c] + (gate == 2 ? 1.0f : 0.0f);   // fold bias + FORGET_BIAS
  }

  // ---- proj: pidx = tid-112 in [0,400): pc = pidx>>1 (col), kp = pidx&1 (k-half) ----
  const int pidx = tid - 112;
  const int pc = pidx >> 1, kp = pidx & 1;
  uint4 pg[7];
  if (pidx >= 0) {
    #pragma unroll
    for (int j = 0; j < 7; ++j) {
      float f[8];
      #pragma unroll
      for (int e = 0; e < 8; ++e) {
        int hk = 8*(kp*7 + j) + e;
        f[e] = (hk < 100) ? P[(size_t)hk*200 + pc] : 0.f;
      }
      pg[j] = make_uint4(pkh(f[0],f[1]), pkh(f[2],f[3]), pkh(f[4],f[5]), pkh(f[6],f[7]));
    }
  }

  // ---- cell threads (c<100): state in register ----
  float cs = 0.f;
  if (c < 100) cs = c0v[(size_t)seq*100 + c];

  // ---- init xp (x(t0) + m0 + pads), h2 pads ----
  if (tid < 50) {
    const float* zz = z + (size_t)seq*40000 + (size_t)(dir ? TB-1 : 0)*100;
    xp[tid] = pkh(zz[2*tid], zz[2*tid+1]);
  } else if (tid >= 64 && tid < 164) {
    int j = tid - 64;
    const float* mm = m0v + (size_t)seq*200;
    xp[50 + j] = pkh(mm[2*j], mm[2*j+1]);
  } else if (tid >= 192 && tid < 194) {
    xp[150 + (tid - 192)] = 0u;
  } else if (tid >= 256 && tid < 262) {
    h2[50 + (tid - 256)] = 0u;
  }
  __syncthreads();

  for (int t = 0; t < TB; ++t) {
    const int tt = dir ? (TB-1-t) : t;

    // x(t+1) prefetch by gates-idle threads 400..499 (hidden across gates+cell)
    float xpre = 0.f;
    if (tid >= 400 && tid < 500 && t+1 < TB) {
      int ttn = dir ? (TB-2-t) : (t+1);
      xpre = z[(size_t)seq*40000 + (size_t)ttn*100 + (tid - 400)];
    }

    // (1) gates: full-K dot per column, 4 independent accumulators, fused activation
    if (c < 400) {
      float a0 = 0.f, a1 = 0.f, a2 = 0.f, a3 = 0.f;
      #pragma unroll
      for (int j = 0; j < 38; ++j) {
        uint4 xv = *(const uint4*)(xp + 4*j);
        a0 = dot2f(wg[j].x, xv.x, a0);
        a1 = dot2f(wg[j].y, xv.y, a1);
        a2 = dot2f(wg[j].z, xv.z, a2);
        a3 = dot2f(wg[j].w, xv.w, a3);
      }
      float af = ((a0 + a1) + (a2 + a3)) + bc;
      // unified activation: tanh(x) = 2*sigmoid(2x)-1 (branch-free)
      float arg = (gate == 1) ? af + af : af;
      float v = sigf(arg);
      ga[c] = (gate == 1) ? 2.0f*v - 1.0f : v;
    }
    __syncthreads();                                   // B: ga (activated) ready

    // (2) cell update + h pack (gate order i,j,f,o)
    if (c < 100) {
      float cc = ga[200+c]*cs + ga[c]*ga[100+c];
      cs = cc;
      float h = ga[300+c]*tanhf_(cc);
      float hn = __shfl_xor(h, 1);
      if ((c & 1) == 0) h2[c >> 1] = pkh(h, hn);
    }
    __syncthreads();                                   // C: h2 ready

    // (3) projection (k-split pair), 4 accumulators + shfl-reduce + out + m-pack
    if (pidx >= 0) {
      float p0 = 0.f, p1 = 0.f, p2 = 0.f, p3 = 0.f;
      #pragma unroll
      for (int j = 0; j < 7; ++j) {
        uint4 hv = *(const uint4*)(h2 + 4*(kp*7 + j));
        p0 = dot2f(pg[j].x, hv.x, p0);
        p1 = dot2f(pg[j].y, hv.y, p1);
        p2 = dot2f(pg[j].z, hv.z, p2);
        p3 = dot2f(pg[j].w, hv.w, p3);
      }
      float p = (p0 + p1) + (p2 + p3);
      float m = p + __shfl_xor(p, 1);                  // sum the two k-halves (tid-pairs)
      if ((pidx & 1) == 0) {                            // even lanes hold m(pc)
        __builtin_nontemporal_store(m, out + (size_t)seq*OUTROW + (size_t)tt*400 + dir*200 + pc);
        float mn = __shfl_xor(m, 2);                   // m(pc^1) (both even lanes active)
        if ((pidx & 2) == 0) xp[50 + (pc >> 1)] = pkh(m, mn);
      }
    }
    // (4) pack x(t+1)
    if (tid >= 400 && tid < 500 && t+1 < TB) {
      float xn = __shfl_xor(xpre, 1);
      if (((tid - 400) & 1) == 0) xp[(tid - 400) >> 1] = pkh(xpre, xn);
    }
    __syncthreads();                                   // A: xp ready for next step
  }
}

extern "C" void kernel_launch(void* const* d_in, const int* in_sizes, int n_in,
                              void* d_out, int out_size, void* d_ws, size_t ws_size,
                              hipStream_t stream) {
  (void)in_sizes; (void)n_in; (void)out_size; (void)d_ws; (void)ws_size;
  lstm_v5<<<GRID, NTHR, 0, stream>>>((const float*)d_in[0],
      (const float*)d_in[1], (const float*)d_in[2],
      (const float*)d_in[3], (const float*)d_in[4],
      (const float*)d_in[5], (const float*)d_in[6], (const float*)d_in[7],
      (const float*)d_in[8], (const float*)d_in[9], (const float*)d_in[10],
      (float*)d_out);
}